// Round 3
// baseline (390.485 us; speedup 1.0000x reference)
//
#include <hip/hip_runtime.h>
#include <math.h>

#define AR_P 48
#define FLEN 168
#define HISTLEN 336

// ws layout (fp32): [0, 8064) W[t][k] (t-major, 48 contiguous per t), [8064, 8232) cc[t]

// One wave. Companion-matrix power recurrence:
//   r_0 = phi;  r_{t+1}[k] = r_t[k-1] + r_t[47]*phi[k]   (r_t[-1] == 0)
//   mu_orig[b,t] = cc[t] + sum_k W[t,k]*(y[b,k]-mu),  cc folds bias/sigma/mu
__global__ void k_coeffs(const float* __restrict__ phi,
                         const float* __restrict__ bias,
                         const float* __restrict__ mu_p,
                         const float* __restrict__ sigma_p,
                         float* __restrict__ ws) {
    const int k = threadIdx.x;  // 64 threads, 1 wave
    float* W  = ws;
    float* cc = ws + AR_P * FLEN;
    const float mu     = mu_p[0];
    const float sigma  = sigma_p[0];
    const float bias_f = bias[0];
    const float phik = (k < AR_P) ? phi[k] : 0.0f;

    float r = phik;     // r_0 = phi
    float csum = 0.0f;  // sum_{m<t} r_m[47]
    for (int t = 0; t < FLEN; ++t) {
        if (k < AR_P) W[t * AR_P + k] = r;
        if (k == 0)   cc[t] = bias_f * (1.0f + csum) * sigma + mu;
        float r47 = __shfl(r, AR_P - 1, 64);
        csum += r47;
        float up = __shfl_up(r, 1, 64);
        float rn = (k == 0 ? 0.0f : up) + r47 * phik;
        r = (k < AR_P) ? rn : 0.0f;
    }
}

// lane = forecast step t (3 steps per lane: t, t+64, t+128).
// W rows live in VGPRs (loaded once per wave); history y is wave-uniform ->
// s_load into SGPRs; stores are lane-contiguous -> fully coalesced.
__global__ __launch_bounds__(256, 2) void k_main(
    const float* __restrict__ enc_l,
    const float* __restrict__ ws,
    const float* __restrict__ mu_p,
    const float* __restrict__ log_sigma2,
    const float* __restrict__ sigma_p,
    float* __restrict__ out,   // [B*168] mu, then [B*168] logvar
    int B, int total_waves) {
    const int lane = threadIdx.x & 63;
    const int wave = __builtin_amdgcn_readfirstlane(
        blockIdx.x * (blockDim.x >> 6) + (threadIdx.x >> 6));
    const int t0 = lane, t1 = lane + 64, t2 = lane + 128;
    const float mu = mu_p[0];

    // Load W rows for this lane's three t's (contiguous 192 B per lane;
    // across the wave this is one dense 32 KB sweep). Reused for all rows.
    float W0[AR_P], W1[AR_P], W2[AR_P];
    {
        const float4* p0 = reinterpret_cast<const float4*>(ws + t0 * AR_P);
        const float4* p1 = reinterpret_cast<const float4*>(ws + t1 * AR_P);
        const float4* p2 = reinterpret_cast<const float4*>(ws + t2 * AR_P);
        const bool v2 = (t2 < FLEN);
#pragma unroll
        for (int i = 0; i < AR_P / 4; ++i) {
            float4 a = p0[i];
            W0[i*4+0]=a.x; W0[i*4+1]=a.y; W0[i*4+2]=a.z; W0[i*4+3]=a.w;
            float4 b = p1[i];
            W1[i*4+0]=b.x; W1[i*4+1]=b.y; W1[i*4+2]=b.z; W1[i*4+3]=b.w;
            if (v2) {
                float4 c = p2[i];
                W2[i*4+0]=c.x; W2[i*4+1]=c.y; W2[i*4+2]=c.z; W2[i*4+3]=c.w;
            } else {
                W2[i*4+0]=0.f; W2[i*4+1]=0.f; W2[i*4+2]=0.f; W2[i*4+3]=0.f;
            }
        }
    }
    // Fold the -mu into the init: base = cc[t] - mu * sum_k W[t][k]
    float s0 = 0.f, s1 = 0.f, s2 = 0.f;
#pragma unroll
    for (int k = 0; k < AR_P; ++k) { s0 += W0[k]; s1 += W1[k]; s2 += W2[k]; }
    const float* cc = ws + AR_P * FLEN;
    const float b0 = cc[t0] - mu * s0;
    const float b1 = cc[t1] - mu * s1;
    const float b2 = (t2 < FLEN ? cc[t2] : 0.f) - mu * s2;

    for (int r = wave; r < B; r += total_waves) {
        // wave-uniform history address -> scalar loads
        const float* y = enc_l + (size_t)r * HISTLEN + (HISTLEN - AR_P);
        float a0 = b0, a1 = b1, a2 = b2;
#pragma unroll
        for (int k = 0; k < AR_P; ++k) {
            const float yk = y[k];   // uniform -> SGPR operand
            a0 = fmaf(W0[k], yk, a0);
            a1 = fmaf(W1[k], yk, a1);
            a2 = fmaf(W2[k], yk, a2);
        }
        float* orow = out + (size_t)r * FLEN;
        orow[t0] = a0;               // lanes contiguous -> coalesced
        orow[t1] = a1;
        if (lane < FLEN - 128) orow[t2] = a2;
    }

    // fused constant logvar fill: coalesced grid-stride float4
    const float lv = log_sigma2[0] + 2.0f * logf(sigma_p[0]);
    const float4 v = make_float4(lv, lv, lv, lv);
    float4* o = reinterpret_cast<float4*>(out + (size_t)B * FLEN);
    const size_t n4 = (size_t)B * FLEN / 4;
    const size_t stride = (size_t)gridDim.x * blockDim.x;
    for (size_t i = (size_t)blockIdx.x * blockDim.x + threadIdx.x; i < n4; i += stride)
        o[i] = v;
}

extern "C" void kernel_launch(void* const* d_in, const int* in_sizes, int n_in,
                              void* d_out, int out_size, void* d_ws, size_t ws_size,
                              hipStream_t stream) {
    const float* enc_l = (const float*)d_in[0];
    // d_in[1..3] = enc_t, enc_w, enc_s (unused by the reference)
    const float* phi  = (const float*)d_in[4];
    const float* bias = (const float*)d_in[5];
    const float* ls2  = (const float*)d_in[6];
    const float* mu   = (const float*)d_in[7];
    const float* sg   = (const float*)d_in[8];
    float* ws  = (float*)d_ws;
    float* out = (float*)d_out;
    const int B = in_sizes[0] / HISTLEN;

    hipLaunchKernelGGL(k_coeffs, dim3(1), dim3(64), 0, stream,
                       phi, bias, mu, sg, ws);
    const int blocks = 512;                 // ~2 blocks/CU resident, grid-stride
    const int total_waves = blocks * (256 / 64);
    hipLaunchKernelGGL(k_main, dim3(blocks), dim3(256), 0, stream,
                       enc_l, ws, mu, ls2, sg, out, B, total_waves);
}